// Round 1
// 523.263 us; speedup vs baseline: 1.0090x; 1.0090x over previous
//
#include <hip/hip_runtime.h>
#include <cstdint>

#define NROWS 8192
#define FDIM  512

typedef __attribute__((ext_vector_type(8))) unsigned short u16x8;
typedef __attribute__((ext_vector_type(8))) __bf16 bf16x8;
typedef __attribute__((ext_vector_type(4))) float f32x4;

__device__ __forceinline__ unsigned short f2bf(float f) {
    unsigned u = __float_as_uint(f);
    u += 0x7fffu + ((u >> 16) & 1u);   // RNE; inputs are finite/normal
    return (unsigned short)(u >> 16);
}

__device__ __forceinline__ float bf2f(unsigned short h) {
    return __uint_as_float((unsigned)h << 16);
}

__device__ __forceinline__ void gload16(const void* g, void* l) {
    __builtin_amdgcn_global_load_lds(
        (__attribute__((address_space(1))) unsigned int*)g,
        (__attribute__((address_space(3))) unsigned int*)l,
        16, 0, 0);
}

// Transpose fp32 -> bf16: gT[i][j] = bf16(graph[j][i]).
// Tile = 128 j-rows x 64 i-cols. Writes 256B contiguous segments (ushort8/lane).
// FUSED: also emits per-jblock column partial sums (fp32) for deg:
//   dpart[blockIdx.y * NROWS + i] = sum_{j in this 128-row block} graph[j][i]
__global__ __launch_bounds__(256) void transpose_bf16_kernel(
    const float* __restrict__ graph, unsigned short* __restrict__ gT,
    float* __restrict__ dpart) {
    __shared__ float tile[128][65];   // [j][i], odd pad: b32 LDS ops, <=4-way banks
    const int t  = threadIdx.x;
    const int i0 = blockIdx.x * 64;
    const int j0 = blockIdx.y * 128;
    {   // phase 1: coalesced float4 reads, 256B/row segments
        const int c4 = (t & 15) * 4;
        const int r  = t >> 4;
        #pragma unroll
        for (int p = 0; p < 8; ++p) {
            const int rr = r + p * 16;   // 0..127
            const float4 v = *(const float4*)&graph[(size_t)(j0 + rr) * NROWS + i0 + c4];
            tile[rr][c4 + 0] = v.x; tile[rr][c4 + 1] = v.y;
            tile[rr][c4 + 2] = v.z; tile[rr][c4 + 3] = v.w;
        }
    }
    __syncthreads();
    {   // phase 2: ushort8 stores, 256B/row segments (16 lanes x 16B) + col sums
        const int ci = t & 15;           // j-chunk: j = ci*8 .. ci*8+7
        const int ir = t >> 4;           // 0..15
        float cs[4];
        #pragma unroll
        for (int p = 0; p < 4; ++p) {
            const int i = ir + p * 16;   // 0..63
            u16x8 o; float c = 0.f;
            #pragma unroll
            for (int q = 0; q < 8; ++q) {
                const float v = tile[ci * 8 + q][i];
                o[q] = f2bf(v);
                c += v;
            }
            *(u16x8*)&gT[(size_t)(i0 + i) * NROWS + j0 + ci * 8] = o;
            cs[p] = c;
        }
        // reduce the 16 ci-chunks (consecutive lanes within one wave) per column
        #pragma unroll
        for (int p = 0; p < 4; ++p) {
            float c = cs[p];
            #pragma unroll
            for (int off = 1; off < 16; off <<= 1) c += __shfl_xor(c, off);
            if (ci == 0)
                dpart[(size_t)blockIdx.y * NROWS + i0 + ir + p * 16] = c;
        }
    }
}

// deg[i] = sum over 64 j-block partials (fp32, deterministic)
__global__ __launch_bounds__(256) void deg_reduce_kernel(
    const float* __restrict__ dpart, float* __restrict__ deg) {
    const int i = blockIdx.x * 256 + threadIdx.x;
    float s = 0.f;
    #pragma unroll
    for (int jb = 0; jb < 64; ++jb) s += dpart[(size_t)jb * NROWS + i];
    deg[i] = s;
}

// Generic transpose (+ optional row scale by rsqrt(deg)) fp32 -> bf16
__global__ __launch_bounds__(256) void transpose_scale_kernel(
    const float* __restrict__ src, unsigned short* __restrict__ dst,
    int rows, int cols, const float* __restrict__ degv) {
    __shared__ float tile[64][65];
    __shared__ float drow[64];
    const int t  = threadIdx.x;
    const int c0 = blockIdx.x * 64;
    const int r0 = blockIdx.y * 64;
    if (t < 64) drow[t] = degv ? rsqrtf(degv[r0 + t]) : 1.0f;
    __syncthreads();
    {
        const int c4 = (t & 15) * 4;
        const int r  = t >> 4;
        #pragma unroll
        for (int p = 0; p < 4; ++p) {
            const int rr = r + p * 16;
            const float4 v = *(const float4*)&src[(size_t)(r0 + rr) * cols + c0 + c4];
            const float s = drow[rr];
            tile[rr][c4 + 0] = v.x * s; tile[rr][c4 + 1] = v.y * s;
            tile[rr][c4 + 2] = v.z * s; tile[rr][c4 + 3] = v.w * s;
        }
    }
    __syncthreads();
    {
        const int jj  = (t & 15) * 4;
        const int c2b = t >> 4;
        #pragma unroll
        for (int p = 0; p < 4; ++p) {
            const int c2 = c2b + p * 16;
            ushort4 o;
            o.x = f2bf(tile[jj + 0][c2]);
            o.y = f2bf(tile[jj + 1][c2]);
            o.z = f2bf(tile[jj + 2][c2]);
            o.w = f2bf(tile[jj + 3][c2]);
            *(ushort4*)&dst[(size_t)(c0 + c2) * rows + r0 + jj] = o;
        }
    }
}

// ---------------------------------------------------------------------------
// Legacy NT GEMM (m97 2-barrier structure), kept for gemm2 and as fallback.
// C[m][n] = sum_k A[m*lda+k]*B[n*ldb+k]; bf16 inputs (k-contiguous).
// BM=128, BN template (64 or 128), BK=64, 256 threads = 2x2 waves.
// MODE 1: fp32 final = rsqrt(deg[row])*acc + bias[col]. MODE 2: fp32 raw partial.
// Now with T1 XCD-aware bijective block swizzle (requires nwg % 8 == 0).
template <int BN, int MODE>
__global__ __launch_bounds__(256) void gemm_nt_kernel(
    const unsigned short* __restrict__ A, const unsigned short* __restrict__ B,
    int klen, int lda, int ldb, float* __restrict__ Cf, size_t zstride,
    const float* __restrict__ degv, const float* __restrict__ bias, int ldc) {
    __shared__ unsigned short As[2 * 128 * 32];    // [ks][m][32]
    __shared__ unsigned short Bs[2 * BN * 32];     // [ks][n][32]
    constexpr int NF = BN / 32;                    // n-fragments per wave
    const int nx = gridDim.x, ny = gridDim.y;
    const int flat = blockIdx.x + nx * (blockIdx.y + ny * blockIdx.z);
    const int swz  = (flat & 7) * ((nx * ny * (int)gridDim.z) >> 3) + (flat >> 3);
    const int bx = swz % nx, by = (swz / nx) % ny, bz = swz / (nx * ny);
    const int t    = threadIdx.x;
    const int w    = t >> 6, lane = t & 63;
    const int wr   = w >> 1, wc = w & 1;
    const int lrow = lane & 15, quad = lane >> 4;
    const int i0   = bx * 128, f0 = by * BN;
    const int kbeg = bz * klen;
    f32x4 acc[4][NF] = {};

    for (int k0 = kbeg; k0 < kbeg + klen; k0 += 64) {
        #pragma unroll
        for (int i = 0; i < 4; ++i) {              // A: 1024 x 16B chunks
            const int q  = t + i * 256;
            const int ks = q >> 9, rem = q & 511;
            const int m  = rem >> 2, kq = rem & 3;
            gload16(&A[(size_t)(i0 + m) * lda + k0 + ks * 32 + kq * 8],
                    &As[(size_t)(w * 64 + i * 256) * 8]);
        }
        #pragma unroll
        for (int i = 0; i < BN / 32; ++i) {        // B: BN*8 x 16B chunks
            const int q  = t + i * 256;
            const int ks = q / (BN * 4), rem = q % (BN * 4);
            const int n  = rem >> 2, kq = rem & 3;
            gload16(&B[(size_t)(f0 + n) * ldb + k0 + ks * 32 + kq * 8],
                    &Bs[(size_t)(w * 64 + i * 256) * 8]);
        }
        __syncthreads();
        #pragma unroll
        for (int ks = 0; ks < 2; ++ks) {
            bf16x8 af[4], bfr[NF];
            #pragma unroll
            for (int mt = 0; mt < 4; ++mt)
                af[mt] = __builtin_bit_cast(bf16x8,
                    *(const u16x8*)&As[ks * 4096 + (wr * 64 + mt * 16 + lrow) * 32 + quad * 8]);
            #pragma unroll
            for (int nt = 0; nt < NF; ++nt)
                bfr[nt] = __builtin_bit_cast(bf16x8,
                    *(const u16x8*)&Bs[ks * (BN * 32) + (wc * (BN / 2) + nt * 16 + lrow) * 32 + quad * 8]);
            #pragma unroll
            for (int mt = 0; mt < 4; ++mt)
                #pragma unroll
                for (int nt = 0; nt < NF; ++nt)
                    acc[mt][nt] = __builtin_amdgcn_mfma_f32_16x16x32_bf16(
                        af[mt], bfr[nt], acc[mt][nt], 0, 0, 0);
        }
        __syncthreads();
    }
    float* __restrict__ Co = Cf + (size_t)bz * zstride;
    // epilogue: C/D layout col=lane&15, row=quad*4+reg (m89-verified)
    #pragma unroll
    for (int mt = 0; mt < 4; ++mt) {
        #pragma unroll
        for (int nt = 0; nt < NF; ++nt) {
            const int col = f0 + wc * (BN / 2) + nt * 16 + lrow;
            #pragma unroll
            for (int r = 0; r < 4; ++r) {
                const int row = i0 + wr * 64 + mt * 16 + quad * 4 + r;
                if (MODE == 1) {
                    const float dsc = rsqrtf(degv[row]);
                    Co[(size_t)row * ldc + col] = dsc * acc[mt][nt][r] + bias[col];
                } else {
                    Co[(size_t)row * ldc + col] = acc[mt][nt][r];
                }
            }
        }
    }
}

// ---------------------------------------------------------------------------
// 256^2 8-phase NT GEMM (T2+T3+T4+T5): BM=BN=256, BK=64, 512 threads = 8 waves
// (wave grid 2x4, per-wave output 128x64). LDS = 128 KiB dynamic:
//   A: [slot][256][64] bf16 at 0; B: same at +32768 elems. Double-buffered.
// Staging: global_load_lds dwordx4, linear LDS dest; bank swizzle applied by
// pre-swizzling the per-lane GLOBAL source k-offset and the ds_read address
// with the same involution (elem_off ^= (row&3)<<4)  [both-sides rule].
// Pipeline invariant entering tile t, phase 1: {Bh1(t), Ah1(t)} in flight
// (4 loads/thread); per tile issues {Ah0,Bh0,Bh1,Ah1} of t+1 into the other
// slot (its previous reads barrier-certified done); vmcnt(4) at ends of
// P1/P2/P4 — never drained to 0 in the main loop. Tail drains 4 -> 2 -> 0.
// Output: fp32 split-K partial (MODE 2 semantics).
// ---------------------------------------------------------------------------
__device__ __forceinline__ void stage_half(
    const unsigned short* __restrict__ G, int ldg, int grow0, int kcol,
    unsigned short* lbase, int h, int w2, int lsub) {
    #pragma unroll
    for (int j = 0; j < 2; ++j) {
        const int r = h * 128 + (w2 + j) * 8;    // 8 rows per gload instr
        gload16(&G[(size_t)(grow0 + r + lsub) * ldg + kcol],
                lbase + (size_t)r * 64);
    }
}

#define G8_READ_A(MH, ASL)                                                       \
    _Pragma("unroll") for (int mt = 0; mt < 4; ++mt)                             \
    _Pragma("unroll") for (int ks = 0; ks < 2; ++ks) {                           \
        const int row_ = (MH) * 128 + wr * 64 + mt * 16 + lrow;                  \
        af[mt][ks] = __builtin_bit_cast(bf16x8,                                  \
            *(const u16x8*)&(ASL)[(size_t)row_ * 64 + ((ks * 32 + quad * 8) ^ rsw)]); }

#define G8_READ_B(NH, BSL)                                                       \
    _Pragma("unroll") for (int nt = 0; nt < 2; ++nt)                             \
    _Pragma("unroll") for (int ks = 0; ks < 2; ++ks) {                           \
        const int row_ = (NH) * 128 + wc * 32 + nt * 16 + lrow;                  \
        bfr[nt][ks] = __builtin_bit_cast(bf16x8,                                 \
            *(const u16x8*)&(BSL)[(size_t)row_ * 64 + ((ks * 32 + quad * 8) ^ rsw)]); }

#define G8_MFMA(Q)                                                               \
    __builtin_amdgcn_s_setprio(1);                                               \
    _Pragma("unroll") for (int mt = 0; mt < 4; ++mt)                             \
    _Pragma("unroll") for (int nt = 0; nt < 2; ++nt)                             \
    _Pragma("unroll") for (int ks = 0; ks < 2; ++ks)                             \
        acc[Q][mt][nt] = __builtin_amdgcn_mfma_f32_16x16x32_bf16(                \
            af[mt][ks], bfr[nt][ks], acc[Q][mt][nt], 0, 0, 0);                   \
    __builtin_amdgcn_s_setprio(0);

#define G8_BAR()     __builtin_amdgcn_s_barrier()
#define G8_WAITV(N)  asm volatile("s_waitcnt vmcnt(" #N ")" ::: "memory")

__global__ __launch_bounds__(512, 2) void gemm8_kernel(
    const unsigned short* __restrict__ A, const unsigned short* __restrict__ B,
    int klen, int lda, int ldb, float* __restrict__ Cf, size_t zstride, int ldc) {
    extern __shared__ unsigned short sh[];
    // T1: XCD-aware bijective block swizzle (nwg % 8 == 0)
    const int nx = gridDim.x, ny = gridDim.y;
    const int flat = blockIdx.x + nx * (blockIdx.y + ny * blockIdx.z);
    const int swz  = (flat & 7) * ((nx * ny * (int)gridDim.z) >> 3) + (flat >> 3);
    const int bx = swz % nx, by = (swz / nx) % ny, bz = swz / (nx * ny);
    const int i0 = bx * 256, f0 = by * 256, kbeg = bz * klen;

    const int t    = threadIdx.x;
    const int w    = t >> 6, lane = t & 63;
    const int wr   = w >> 2, wc = w & 3;          // 2x4 wave grid
    const int lrow = lane & 15, quad = lane >> 4;
    const int rsw  = (lrow & 3) << 4;             // read-side swizzle (elems)
    const int lsub = lane >> 3, kq = lane & 7;
    const int kof  = (kq * 8) ^ ((lsub & 3) << 4); // source-side swizzle (elems)
    const int w2   = w * 2;

    f32x4  acc[4][4][2] = {};                     // [quadrant][mt][nt]
    bf16x8 af[4][2], bfr[2][2];

    // prologue: tile 0 into slot 0; order must match in-loop issue order
    stage_half(A, lda, i0, kbeg + kof, sh,         0, w2, lsub);
    stage_half(B, ldb, f0, kbeg + kof, sh + 32768, 0, w2, lsub);
    stage_half(B, ldb, f0, kbeg + kof, sh + 32768, 1, w2, lsub);
    stage_half(A, lda, i0, kbeg + kof, sh,         1, w2, lsub);
    G8_WAITV(4);
    G8_BAR();

    const int NT = klen >> 6;
    for (int tt = 0; tt < NT - 1; ++tt) {
        const int s = tt & 1, sn = s ^ 1;
        unsigned short* Asl  = sh + s  * 16384;
        unsigned short* Bsl  = sh + 32768 + s  * 16384;
        unsigned short* AslN = sh + sn * 16384;
        unsigned short* BslN = sh + 32768 + sn * 16384;
        const int kn = kbeg + (tt + 1) * 64 + kof;
        // P1: quadrant (mh0, nh0)
        G8_READ_A(0, Asl); G8_READ_B(0, Bsl);
        stage_half(A, lda, i0, kn, AslN, 0, w2, lsub);
        G8_BAR();
        G8_MFMA(0);
        G8_WAITV(4); G8_BAR();
        // P2: (mh0, nh1)
        G8_READ_B(1, Bsl);
        stage_half(B, ldb, f0, kn, BslN, 0, w2, lsub);
        G8_BAR();
        G8_MFMA(1);
        G8_WAITV(4); G8_BAR();
        // P3: (mh1, nh1) — A-half1 fresh, B-half1 frags still live
        G8_READ_A(1, Asl);
        stage_half(B, ldb, f0, kn, BslN, 1, w2, lsub);
        G8_BAR();
        G8_MFMA(2);
        G8_BAR();
        // P4: (mh1, nh0) — re-read B-half0 (landed long ago)
        G8_READ_B(0, Bsl);
        stage_half(A, lda, i0, kn, AslN, 1, w2, lsub);
        G8_BAR();
        G8_MFMA(3);
        G8_WAITV(4); G8_BAR();
    }
    {   // tail tile: no staging; drain 4 -> 2 -> 0
        const int s = (NT - 1) & 1;
        unsigned short* Asl = sh + s * 16384;
        unsigned short* Bsl = sh + 32768 + s * 16384;
        G8_READ_A(0, Asl); G8_READ_B(0, Bsl);
        G8_BAR(); G8_MFMA(0); G8_WAITV(2); G8_BAR();
        G8_READ_B(1, Bsl);
        G8_BAR(); G8_MFMA(1); G8_WAITV(0); G8_BAR();
        G8_READ_A(1, Asl);
        G8_BAR(); G8_MFMA(2); G8_BAR();
        G8_READ_B(0, Bsl);
        G8_BAR(); G8_MFMA(3);
    }

    float* __restrict__ Co = Cf + (size_t)bz * zstride;
    // C/D layout col=lane&15, row=quad*4+reg (m89-verified)
    #pragma unroll
    for (int q = 0; q < 4; ++q) {
        const int mh = (q >= 2) ? 1 : 0;
        const int nh = (q == 1 || q == 2) ? 1 : 0;
        #pragma unroll
        for (int mt = 0; mt < 4; ++mt) {
            #pragma unroll
            for (int nt = 0; nt < 2; ++nt) {
                const int col = f0 + nh * 128 + wc * 32 + nt * 16 + lrow;
                #pragma unroll
                for (int r = 0; r < 4; ++r) {
                    const int row = i0 + mh * 128 + wr * 64 + mt * 16 + quad * 4 + r;
                    Co[(size_t)row * ldc + col] = acc[q][mt][nt][r];
                }
            }
        }
    }
}

// Tb[idx] = bf16(sum over 4 split-K fp32 partials)
__global__ __launch_bounds__(256) void reduce4_kernel(
    const float4* __restrict__ P, unsigned short* __restrict__ Tb) {
    const size_t stride = (size_t)NROWS * FDIM / 4;   // float4 elems per partial
    #pragma unroll
    for (int p = 0; p < 4; ++p) {
        const size_t idx = (size_t)blockIdx.x * 1024 + p * 256 + threadIdx.x;
        const float4 a = P[idx];
        const float4 b = P[idx + stride];
        const float4 c = P[idx + 2 * stride];
        const float4 d = P[idx + 3 * stride];
        ushort4 o;
        o.x = f2bf(a.x + b.x + c.x + d.x);
        o.y = f2bf(a.y + b.y + c.y + d.y);
        o.z = f2bf(a.z + b.z + c.z + d.z);
        o.w = f2bf(a.w + b.w + c.w + d.w);
        *(ushort4*)&Tb[idx * 4] = o;
    }
}

extern "C" void kernel_launch(void* const* d_in, const int* in_sizes, int n_in,
                              void* d_out, int out_size, void* d_ws, size_t ws_size,
                              hipStream_t stream) {
    const float* x      = (const float*)d_in[0];
    const float* graph  = (const float*)d_in[1];
    const float* weight = (const float*)d_in[2];
    const float* bias   = (const float*)d_in[3];
    float* out = (float*)d_out;

    char* ws = (char*)d_ws;
    const size_t GT_B  = (size_t)NROWS * NROWS * 2;   // 134.2 MB: gT bf16
    const size_t XST_B = (size_t)FDIM * NROWS * 2;    // 8.4 MB: xsT bf16
    const size_t WT_B  = (size_t)FDIM * FDIM * 2;     // 0.5 MB: wT bf16
    const size_t TB_B  = (size_t)NROWS * FDIM * 2;    // 8.4 MB: Tb bf16
    const size_t DEG_B = (size_t)NROWS * 4;           // deg fp32 (padded region)
    const size_t P_B   = (size_t)NROWS * FDIM * 4 * 4; // 64 MB: split-K partials
    unsigned short* gT  = (unsigned short*)(ws);
    unsigned short* xsT = (unsigned short*)(ws + GT_B);
    unsigned short* wT  = (unsigned short*)(ws + GT_B + XST_B);
    unsigned short* Tb  = (unsigned short*)(ws + GT_B + XST_B + WT_B);
    float* deg          = (float*)(ws + GT_B + XST_B + WT_B + TB_B);
    float* P            = (float*)(ws + GT_B + XST_B + WT_B + TB_B + 32768);
    float* dpart        = (float*)(ws + GT_B + XST_B + WT_B + TB_B + 32768 + P_B); // 2 MB

    hipLaunchKernelGGL(transpose_bf16_kernel, dim3(NROWS / 64, NROWS / 128), dim3(256), 0, stream,
                       graph, gT, dpart);
    hipLaunchKernelGGL(deg_reduce_kernel, dim3(NROWS / 256), dim3(256), 0, stream, dpart, deg);
    hipLaunchKernelGGL(transpose_scale_kernel, dim3(FDIM / 64, NROWS / 64), dim3(256), 0, stream,
                       x, xsT, NROWS, FDIM, deg);
    hipLaunchKernelGGL(transpose_scale_kernel, dim3(FDIM / 64, FDIM / 64), dim3(256), 0, stream,
                       weight, wT, FDIM, FDIM, (const float*)nullptr);

    // T = G^T @ (d^-1/2 * x): M=8192, N=512, K=8192, split-K=4 -> fp32 partials
    // Primary: 256^2 8-phase kernel (128 KiB dynamic LDS); fallback: legacy 128^2.
    hipError_t aerr = hipFuncSetAttribute((const void*)gemm8_kernel,
        hipFuncAttributeMaxDynamicSharedMemorySize, 131072);
    bool use8 = (aerr == hipSuccess);
    if (use8) {
        hipLaunchKernelGGL(gemm8_kernel, dim3(NROWS / 256, FDIM / 256, 4), dim3(512), 131072, stream,
                           gT, xsT, NROWS / 4, NROWS, NROWS, P, (size_t)NROWS * FDIM, FDIM);
        use8 = (hipGetLastError() == hipSuccess);
    }
    if (!use8) {
        hipLaunchKernelGGL((gemm_nt_kernel<128, 2>), dim3(NROWS / 128, FDIM / 128, 4), dim3(256), 0, stream,
                           gT, xsT, NROWS / 4, NROWS, NROWS, P, (size_t)NROWS * FDIM,
                           (const float*)nullptr, (const float*)nullptr, FDIM);
    }

    hipLaunchKernelGGL(reduce4_kernel, dim3(NROWS * FDIM / 4096), dim3(256), 0, stream,
                       (const float4*)P, Tb);
    // y = diag(d^-1/2) * (T @ W) + bias:  M=8192, N=512, K=512
    hipLaunchKernelGGL((gemm_nt_kernel<64, 1>), dim3(NROWS / 128, FDIM / 64, 1), dim3(256), 0, stream,
                       Tb, wT, FDIM, FDIM, FDIM, out, (size_t)0,
                       deg, bias, FDIM);
}